// Round 5
// baseline (407.282 us; speedup 1.0000x reference)
//
#include <hip/hip_runtime.h>

#define ROWS 1024
#define COLS 1024
#define NN (ROWS*COLS)

// R10 hybrid: block stages 48x48 region (phi/inv/runoff/qin) into LDS once
// (1 barrier), then 4 waves each hold a 32x32 sub-region in registers and
// free-run 8 Jacobi steps via shuffles (R9's verified step loop). Output
// 32x32 per block.
#define HALO  8
#define BOT   32               // block output tile (32x32)
#define RH    48               // staged region = BOT + 2*HALO
#define RWP   52               // padded LDS row stride (floats)
#define SPR   (RH/4)           // 12 float4 strips per region row
#define NSTRIP (RH*SPR)        // 576 strips per plane
#define NT    256
#define TPD   (COLS/BOT)       // 32 blocks per dimension

static constexpr float RHOG    = 1000.0f * 9.81f;
static constexpr float INV_SEC = 1.0f / 31556926.0f;
static constexpr float FLOWC   = 0.0405f;

__device__ __forceinline__ float4 gld4(const float* __restrict__ p, int g, bool in) {
    if (in) return *reinterpret_cast<const float4*>(p + g);
    return make_float4(0.f, 0.f, 0.f, 0.f);
}

// ---- prologue: phi, inv_total, runoff -------------------------------------
__global__ __launch_bounds__(256) void k_pre(
        const float* __restrict__ bed, const float* __restrict__ pw,
        const int* __restrict__ status,
        const float* __restrict__ melt, const float* __restrict__ area,
        float* __restrict__ phi, float* __restrict__ inv,
        float* __restrict__ runoff) {
    int i = blockIdx.x * 256 + threadIdx.x;
    int r = i >> 10, c = i & (COLS - 1);
    float p = RHOG * bed[i] + pw[i];
    float t = 0.f;
    if (c > 0)        t += fmaxf(p - (RHOG * bed[i - 1]    + pw[i - 1]),    0.f);
    if (c < COLS - 1) t += fmaxf(p - (RHOG * bed[i + 1]    + pw[i + 1]),    0.f);
    if (r > 0)        t += fmaxf(p - (RHOG * bed[i - COLS] + pw[i - COLS]), 0.f);
    if (r < ROWS - 1) t += fmaxf(p - (RHOG * bed[i + COLS] + pw[i + COLS]), 0.f);
    phi[i]    = p;
    inv[i]    = (status[i] == 0 && t > 0.f) ? (1.f / t) : 0.f;
    runoff[i] = melt[i] * area[i] * INV_SEC;
}

// ---- 8-step: LDS-staged region, register-resident waves, 1 barrier --------
template <bool FIRST, bool FINAL>
__global__ __launch_bounds__(NT, 4) void k_step(
        const float* __restrict__ phi_g, const float* __restrict__ inv_g,
        const float* __restrict__ run_g, const float* __restrict__ qin,
        float* __restrict__ qout,
        const float* __restrict__ cond, const int* __restrict__ status) {
    __shared__ __align__(16) float sP[RH * RWP];
    __shared__ __align__(16) float sV[RH * RWP];
    __shared__ __align__(16) float sR[RH * RWP];
    __shared__ __align__(16) float sQ[RH * RWP];

    const int tid = threadIdx.x;
    const int GR0 = (int)blockIdx.y * BOT - HALO;
    const int GC0 = (int)blockIdx.x * BOT - HALO;

    // ---- stage 4 planes (48x48 region) ------------------------------------
#pragma unroll
    for (int k = 0; k < 3; ++k) {
        int s = tid + k * NT;
        if (s < NSTRIP) {
            int sr = s / SPR, sc4 = (s - sr * SPR) * 4;
            int gr = GR0 + sr, gc = GC0 + sc4;
            bool in = ((unsigned)gr < ROWS) & ((unsigned)gc < COLS);
            int g = gr * COLS + gc;
            int x = sr * RWP + sc4;
            *reinterpret_cast<float4*>(&sP[x]) = gld4(phi_g, g, in);
            *reinterpret_cast<float4*>(&sV[x]) = gld4(inv_g, g, in);
            float4 r4 = gld4(run_g, g, in);
            *reinterpret_cast<float4*>(&sR[x]) = r4;
            *reinterpret_cast<float4*>(&sQ[x]) = FIRST ? r4 : gld4(qin, g, in);
        }
    }
    __syncthreads();           // the only barrier

    // ---- wave geometry: 2x2 waves, each 32x32 region, 8x8 lanes x 4x4 -----
    const int lane = tid & 63;
    const int w  = tid >> 6;
    const int vr = w >> 1, vc = w & 1;
    const int wr = lane >> 3, wc = lane & 7;
    const int lr0 = vr * 16 + wr * 4;      // region-local row of lane block
    const int lc0 = vc * 16 + wc * 4;

    const int upL = (wr > 0) ? lane - 8 : lane;
    const int dnL = (wr < 7) ? lane + 8 : lane;
    const int lfL = (wc > 0) ? lane - 1 : lane;
    const int rtL = (wc < 7) ? lane + 1 : lane;

    // ---- phi/inv into registers + halo from LDS; weights ------------------
    float ph[4][4], iv[4][4];
#pragma unroll
    for (int i = 0; i < 4; ++i) {
        int x = (lr0 + i) * RWP + lc0;
        float4 p4 = *reinterpret_cast<const float4*>(&sP[x]);
        float4 i4 = *reinterpret_cast<const float4*>(&sV[x]);
        ph[i][0]=p4.x; ph[i][1]=p4.y; ph[i][2]=p4.z; ph[i][3]=p4.w;
        iv[i][0]=i4.x; iv[i][1]=i4.y; iv[i][2]=i4.z; iv[i][3]=i4.w;
    }
    // clamped at block-region rim only (depth-0 cells: garbage allowed)
    const int ru = (lr0 > 0)       ? lr0 - 1 : 0;
    const int rd = (lr0 + 4 < RH)  ? lr0 + 4 : RH - 1;
    const int cl = (lc0 > 0)       ? lc0 - 1 : 0;
    const int cr = (lc0 + 4 < RH)  ? lc0 + 4 : RH - 1;
    float phU[4], phD[4], ivU[4], ivD[4], phL[4], phR[4], ivL[4], ivR[4];
    {
        float4 p4 = *reinterpret_cast<const float4*>(&sP[ru * RWP + lc0]);
        float4 i4 = *reinterpret_cast<const float4*>(&sV[ru * RWP + lc0]);
        phU[0]=p4.x; phU[1]=p4.y; phU[2]=p4.z; phU[3]=p4.w;
        ivU[0]=i4.x; ivU[1]=i4.y; ivU[2]=i4.z; ivU[3]=i4.w;
        p4 = *reinterpret_cast<const float4*>(&sP[rd * RWP + lc0]);
        i4 = *reinterpret_cast<const float4*>(&sV[rd * RWP + lc0]);
        phD[0]=p4.x; phD[1]=p4.y; phD[2]=p4.z; phD[3]=p4.w;
        ivD[0]=i4.x; ivD[1]=i4.y; ivD[2]=i4.z; ivD[3]=i4.w;
    }
#pragma unroll
    for (int i = 0; i < 4; ++i) {
        phL[i] = sP[(lr0 + i) * RWP + cl];  ivL[i] = sV[(lr0 + i) * RWP + cl];
        phR[i] = sP[(lr0 + i) * RWP + cr];  ivR[i] = sV[(lr0 + i) * RWP + cr];
    }

    float wW[4][4], wE[4][4], wN[4][4], wS[4][4];
#pragma unroll
    for (int i = 0; i < 4; ++i)
#pragma unroll
        for (int j = 0; j < 4; ++j) {
            float pc = ph[i][j];
            float pu = (i > 0) ? ph[i-1][j] : phU[j];
            float iu = (i > 0) ? iv[i-1][j] : ivU[j];
            float pd = (i < 3) ? ph[i+1][j] : phD[j];
            float id = (i < 3) ? iv[i+1][j] : ivD[j];
            float pl = (j > 0) ? ph[i][j-1] : phL[i];
            float il = (j > 0) ? iv[i][j-1] : ivL[i];
            float pr = (j < 3) ? ph[i][j+1] : phR[i];
            float ir = (j < 3) ? iv[i][j+1] : ivR[i];
            wN[i][j] = fmaxf(pu - pc, 0.f) * iu;
            wS[i][j] = fmaxf(pd - pc, 0.f) * id;
            wW[i][j] = fmaxf(pl - pc, 0.f) * il;
            wE[i][j] = fmaxf(pr - pc, 0.f) * ir;
        }

    // ---- q0 / runoff from LDS ---------------------------------------------
    float q[4][4], ro[4][4];
#pragma unroll
    for (int i = 0; i < 4; ++i) {
        int x = (lr0 + i) * RWP + lc0;
        float4 r4 = *reinterpret_cast<const float4*>(&sR[x]);
        float4 q4 = *reinterpret_cast<const float4*>(&sQ[x]);
        ro[i][0]=r4.x; ro[i][1]=r4.y; ro[i][2]=r4.z; ro[i][3]=r4.w;
        q[i][0]=q4.x;  q[i][1]=q4.y;  q[i][2]=q4.z;  q[i][3]=q4.w;
    }

    // ---- 8 Jacobi steps: 16 shuffles + 64 FMA per lane, no barriers -------
#pragma unroll
    for (int s = 0; s < HALO; ++s) {
        float u[4], d[4], l[4], r[4];
#pragma unroll
        for (int j = 0; j < 4; ++j) {
            u[j] = __shfl(q[3][j], upL, 64);
            d[j] = __shfl(q[0][j], dnL, 64);
        }
#pragma unroll
        for (int i = 0; i < 4; ++i) {
            l[i] = __shfl(q[i][3], lfL, 64);
            r[i] = __shfl(q[i][0], rtL, 64);
        }
        float nq[4][4];
#pragma unroll
        for (int i = 0; i < 4; ++i)
#pragma unroll
            for (int j = 0; j < 4; ++j) {
                float uv = (i > 0) ? q[i-1][j] : u[j];
                float dv = (i < 3) ? q[i+1][j] : d[j];
                float lv = (j > 0) ? q[i][j-1] : l[i];
                float rv = (j < 3) ? q[i][j+1] : r[i];
                float a = ro[i][j];
                a = fmaf(wW[i][j], lv, a);
                a = fmaf(wE[i][j], rv, a);
                a = fmaf(wN[i][j], uv, a);
                a = fmaf(wS[i][j], dv, a);
                nq[i][j] = a;
            }
#pragma unroll
        for (int i = 0; i < 4; ++i)
#pragma unroll
            for (int j = 0; j < 4; ++j) q[i][j] = nq[i][j];
    }

    // ---- write central 16x16 per wave (lanes wr,wc in [2,6)) --------------
    if ((wr >= 2) & (wr < 6) & (wc >= 2) & (wc < 6)) {
#pragma unroll
        for (int i = 0; i < 4; ++i) {
            int go = (GR0 + lr0 + i) * COLS + (GC0 + lc0);   // always in-grid
            if (FINAL) {
                float4 c4 = *reinterpret_cast<const float4*>(cond + go);
                int4 st   = *reinterpret_cast<const int4*>(status + go);
                float4 o;
                float t;
                t = q[i][0] * FLOWC * (c4.x * sqrtf(sqrtf(c4.x))); o.x = (st.x == 0) ? t * t : 0.f;
                t = q[i][1] * FLOWC * (c4.y * sqrtf(sqrtf(c4.y))); o.y = (st.y == 0) ? t * t : 0.f;
                t = q[i][2] * FLOWC * (c4.z * sqrtf(sqrtf(c4.z))); o.z = (st.z == 0) ? t * t : 0.f;
                t = q[i][3] * FLOWC * (c4.w * sqrtf(sqrtf(c4.w))); o.w = (st.w == 0) ? t * t : 0.f;
                *reinterpret_cast<float4*>(qout + go) = o;
            } else {
                *reinterpret_cast<float4*>(qout + go) =
                    make_float4(q[i][0], q[i][1], q[i][2], q[i][3]);
            }
        }
    }
}

extern "C" void kernel_launch(void* const* d_in, const int* in_sizes, int n_in,
                              void* d_out, int out_size, void* d_ws, size_t ws_size,
                              hipStream_t stream) {
    const float* melt   = (const float*)d_in[0];
    const float* bed    = (const float*)d_in[1];
    const float* pw     = (const float*)d_in[2];
    const float* area   = (const float*)d_in[3];
    const float* cond   = (const float*)d_in[4];
    const int*   status = (const int*)d_in[5];
    float* out = (float*)d_out;

    char* ws = (char*)d_ws;
    float* phi    = (float*)(ws);                 //  4 MB
    float* inv    = (float*)(ws + 4ull  * NN);    //  4 MB
    float* runoff = (float*)(ws + 8ull  * NN);    //  4 MB
    float* qA     = (float*)(ws + 12ull * NN);    //  4 MB
    float* qB     = (float*)(ws + 16ull * NN);    //  4 MB (20 MB total)

    k_pre<<<dim3(NN / 256), dim3(256), 0, stream>>>(bed, pw, status, melt, area,
                                                    phi, inv, runoff);

    dim3 grid(TPD, TPD), block(NT);
    k_step<true,  false><<<grid, block, 0, stream>>>(phi, inv, runoff, runoff, qA, nullptr, nullptr);
    k_step<false, false><<<grid, block, 0, stream>>>(phi, inv, runoff, qA, qB, nullptr, nullptr);
    k_step<false, false><<<grid, block, 0, stream>>>(phi, inv, runoff, qB, qA, nullptr, nullptr);
    k_step<false, true ><<<grid, block, 0, stream>>>(phi, inv, runoff, qA, out, cond, status);
}

// Round 6
// 150.086 us; speedup vs baseline: 2.7137x; 2.7137x over previous
//
#include <hip/hip_runtime.h>

#define ROWS 1024
#define COLS 1024
#define NN (ROWS*COLS)

// R11: wave-autonomous 32x32 regions (R9 skeleton, which PASSED), de-spilled:
//  - signed-link weights: 40 regs instead of 64 directed weights
//  - step loop NOT unrolled (#pragma unroll 1) to keep live ranges tight
//  - persistent ~72 VGPR, peak ~110 < 170 cap from __launch_bounds__(256,3)
// 8x8 lane grid x 4x4 cells/lane; per step 16 shuffles + (4 max + 4 fma)/cell.
// No LDS, no barriers.
#define OT    16               // output tile per wave
#define HALO  8
#define TPD   (COLS/OT)        // 64 tiles per dimension
#define WPB   4                // waves per block
#define NT    (WPB*64)         // 256 threads
#define NBLK  ((TPD*TPD)/WPB)  // 1024 blocks

static constexpr float RHOG    = 1000.0f * 9.81f;
static constexpr float INV_SEC = 1.0f / 31556926.0f;
static constexpr float FLOWC   = 0.0405f;

__device__ __forceinline__ float4 gld4(const float* __restrict__ p, int g, bool in) {
    if (in) return *reinterpret_cast<const float4*>(p + g);
    return make_float4(0.f, 0.f, 0.f, 0.f);
}

// ---- prologue: phi, inv_total, runoff -------------------------------------
__global__ __launch_bounds__(256) void k_pre(
        const float* __restrict__ bed, const float* __restrict__ pw,
        const int* __restrict__ status,
        const float* __restrict__ melt, const float* __restrict__ area,
        float* __restrict__ phi, float* __restrict__ inv,
        float* __restrict__ runoff) {
    int i = blockIdx.x * 256 + threadIdx.x;
    int r = i >> 10, c = i & (COLS - 1);
    float p = RHOG * bed[i] + pw[i];
    float t = 0.f;
    if (c > 0)        t += fmaxf(p - (RHOG * bed[i - 1]    + pw[i - 1]),    0.f);
    if (c < COLS - 1) t += fmaxf(p - (RHOG * bed[i + 1]    + pw[i + 1]),    0.f);
    if (r > 0)        t += fmaxf(p - (RHOG * bed[i - COLS] + pw[i - COLS]), 0.f);
    if (r < ROWS - 1) t += fmaxf(p - (RHOG * bed[i + COLS] + pw[i + COLS]), 0.f);
    phi[i]    = p;
    inv[i]    = (status[i] == 0 && t > 0.f) ? (1.f / t) : 0.f;
    runoff[i] = melt[i] * area[i] * INV_SEC;
}

// ---- 8-step register-resident Jacobi, one wave per 32x32 region -----------
template <bool FIRST, bool FINAL>
__global__ __launch_bounds__(NT, 3) void k_step(
        const float* __restrict__ phi_g, const float* __restrict__ inv_g,
        const float* __restrict__ run_g, const float* __restrict__ qin,
        float* __restrict__ qout,
        const float* __restrict__ cond, const int* __restrict__ status) {
    const int tid  = threadIdx.x;
    const int lane = tid & 63;
    const int wid  = blockIdx.x * WPB + (tid >> 6);
    const int tr = wid >> 6, tc = wid & (TPD - 1);
    const int R0 = tr * OT - HALO, C0 = tc * OT - HALO;
    const int wr = lane >> 3, wc = lane & 7;            // 8 x 8 lane grid
    const int gr0 = R0 + wr * 4, gc0 = C0 + wc * 4;     // lane's 4x4 block

    // clamped shuffle sources (rim lanes read self: garbage past depth, fine)
    const int upL = (wr > 0) ? lane - 8 : lane;
    const int dnL = (wr < 7) ? lane + 8 : lane;
    const int lfL = (wc > 0) ? lane - 1 : lane;
    const int rtL = (wc < 7) ? lane + 1 : lane;

    const bool cin = ((unsigned)gc0 < COLS);

    // ---- stage phi/inv for this lane's 4x4 cells --------------------------
    float ph[4][4], iv[4][4];
#pragma unroll
    for (int i = 0; i < 4; ++i) {
        bool in = ((unsigned)(gr0 + i) < ROWS) & cin;
        int  g  = (gr0 + i) * COLS + gc0;
        float4 p4 = gld4(phi_g, g, in);
        float4 i4 = gld4(inv_g, g, in);
        ph[i][0]=p4.x; ph[i][1]=p4.y; ph[i][2]=p4.z; ph[i][3]=p4.w;
        iv[i][0]=i4.x; iv[i][1]=i4.y; iv[i][2]=i4.z; iv[i][3]=i4.w;
    }

    // halo phi/inv via shuffles (setup only)
    float phU[4], phD[4], ivU[4], ivD[4], phL[4], phR[4], ivL[4], ivR[4];
#pragma unroll
    for (int j = 0; j < 4; ++j) {
        phU[j] = __shfl(ph[3][j], upL, 64);  ivU[j] = __shfl(iv[3][j], upL, 64);
        phD[j] = __shfl(ph[0][j], dnL, 64);  ivD[j] = __shfl(iv[0][j], dnL, 64);
    }
#pragma unroll
    for (int i = 0; i < 4; ++i) {
        phL[i] = __shfl(ph[i][3], lfL, 64);  ivL[i] = __shfl(iv[i][3], lfL, 64);
        phR[i] = __shfl(ph[i][0], rtL, 64);  ivR[i] = __shfl(iv[i][0], rtL, 64);
    }

    // ---- signed link weights (40 regs). For a link a->b with s=phi_a-phi_b:
    // W = s>0 ? s*inv_a : s*inv_b. Flow a->b contributes max(W,0)*q_a to b;
    // flow b->a contributes max(-W,0)*q_b to a. (ph/iv die here.)
    float WH[4][4];   // west link of cell (i,j): (i,j-1)->(i,j)
    float WV[4][4];   // north link of cell (i,j): (i-1,j)->(i,j)
    float EH[4];      // east link of cell (i,3): (i,3)->(i,4)
    float SV[4];      // south link of cell (3,j): (3,j)->(4,j)
#pragma unroll
    for (int i = 0; i < 4; ++i)
#pragma unroll
        for (int j = 0; j < 4; ++j) {
            float pw_ = (j > 0) ? ph[i][j-1] : phL[i];
            float iw_ = (j > 0) ? iv[i][j-1] : ivL[i];
            float s   = pw_ - ph[i][j];
            WH[i][j]  = s * ((s > 0.f) ? iw_ : iv[i][j]);
            float pn_ = (i > 0) ? ph[i-1][j] : phU[j];
            float in_ = (i > 0) ? iv[i-1][j] : ivU[j];
            float sv  = pn_ - ph[i][j];
            WV[i][j]  = sv * ((sv > 0.f) ? in_ : iv[i][j]);
        }
#pragma unroll
    for (int i = 0; i < 4; ++i) {
        float s = ph[i][3] - phR[i];
        EH[i] = s * ((s > 0.f) ? iv[i][3] : ivR[i]);
    }
#pragma unroll
    for (int j = 0; j < 4; ++j) {
        float s = ph[3][j] - phD[j];
        SV[j] = s * ((s > 0.f) ? iv[3][j] : ivD[j]);
    }

    // ---- runoff + q0 ------------------------------------------------------
    float q[4][4], ro[4][4];
#pragma unroll
    for (int i = 0; i < 4; ++i) {
        bool in = ((unsigned)(gr0 + i) < ROWS) & cin;
        int  g  = (gr0 + i) * COLS + gc0;
        float4 r4 = gld4(run_g, g, in);
        ro[i][0]=r4.x; ro[i][1]=r4.y; ro[i][2]=r4.z; ro[i][3]=r4.w;
        if (FIRST) {
            q[i][0]=r4.x; q[i][1]=r4.y; q[i][2]=r4.z; q[i][3]=r4.w;
        } else {
            float4 q4 = gld4(qin, g, in);
            q[i][0]=q4.x; q[i][1]=q4.y; q[i][2]=q4.z; q[i][3]=q4.w;
        }
    }

    // ---- 8 Jacobi steps (rolled loop, tight live ranges) ------------------
#pragma unroll 1
    for (int s = 0; s < HALO; ++s) {
        float u[4], d[4], l[4], r[4];
#pragma unroll
        for (int j = 0; j < 4; ++j) {
            u[j] = __shfl(q[3][j], upL, 64);
            d[j] = __shfl(q[0][j], dnL, 64);
        }
#pragma unroll
        for (int i = 0; i < 4; ++i) {
            l[i] = __shfl(q[i][3], lfL, 64);
            r[i] = __shfl(q[i][0], rtL, 64);
        }
        float nq[4][4];
#pragma unroll
        for (int i = 0; i < 4; ++i)
#pragma unroll
            for (int j = 0; j < 4; ++j) {
                float qw = (j > 0) ? q[i][j-1] : l[i];
                float qe = (j < 3) ? q[i][j+1] : r[i];
                float qn = (i > 0) ? q[i-1][j] : u[j];
                float qs = (i < 3) ? q[i+1][j] : d[j];
                float We = (j < 3) ? WH[i][j+1] : EH[i];
                float Ws = (i < 3) ? WV[i+1][j] : SV[j];
                float a = ro[i][j];
                a = fmaf(fmaxf(WH[i][j], 0.f), qw, a);
                a = fmaf(fmaxf(-We,      0.f), qe, a);
                a = fmaf(fmaxf(WV[i][j], 0.f), qn, a);
                a = fmaf(fmaxf(-Ws,      0.f), qs, a);
                nq[i][j] = a;
            }
#pragma unroll
        for (int i = 0; i < 4; ++i)
#pragma unroll
            for (int j = 0; j < 4; ++j) q[i][j] = nq[i][j];
    }

    // ---- write the central 16x16 (lanes wr,wc in [2,6)) -------------------
    if ((wr >= 2) & (wr < 6) & (wc >= 2) & (wc < 6)) {
#pragma unroll
        for (int i = 0; i < 4; ++i) {
            int go = (gr0 + i) * COLS + gc0;          // always in-grid here
            if (FINAL) {
                float4 c4 = *reinterpret_cast<const float4*>(cond + go);
                int4 st   = *reinterpret_cast<const int4*>(status + go);
                float4 o;
                float t;
                t = q[i][0] * FLOWC * (c4.x * sqrtf(sqrtf(c4.x))); o.x = (st.x == 0) ? t * t : 0.f;
                t = q[i][1] * FLOWC * (c4.y * sqrtf(sqrtf(c4.y))); o.y = (st.y == 0) ? t * t : 0.f;
                t = q[i][2] * FLOWC * (c4.z * sqrtf(sqrtf(c4.z))); o.z = (st.z == 0) ? t * t : 0.f;
                t = q[i][3] * FLOWC * (c4.w * sqrtf(sqrtf(c4.w))); o.w = (st.w == 0) ? t * t : 0.f;
                *reinterpret_cast<float4*>(qout + go) = o;
            } else {
                *reinterpret_cast<float4*>(qout + go) =
                    make_float4(q[i][0], q[i][1], q[i][2], q[i][3]);
            }
        }
    }
}

extern "C" void kernel_launch(void* const* d_in, const int* in_sizes, int n_in,
                              void* d_out, int out_size, void* d_ws, size_t ws_size,
                              hipStream_t stream) {
    const float* melt   = (const float*)d_in[0];
    const float* bed    = (const float*)d_in[1];
    const float* pw     = (const float*)d_in[2];
    const float* area   = (const float*)d_in[3];
    const float* cond   = (const float*)d_in[4];
    const int*   status = (const int*)d_in[5];
    float* out = (float*)d_out;

    char* ws = (char*)d_ws;
    float* phi    = (float*)(ws);                 //  4 MB
    float* inv    = (float*)(ws + 4ull  * NN);    //  4 MB
    float* runoff = (float*)(ws + 8ull  * NN);    //  4 MB
    float* qA     = (float*)(ws + 12ull * NN);    //  4 MB
    float* qB     = (float*)(ws + 16ull * NN);    //  4 MB (20 MB total)

    k_pre<<<dim3(NN / 256), dim3(256), 0, stream>>>(bed, pw, status, melt, area,
                                                    phi, inv, runoff);

    dim3 grid(NBLK), block(NT);
    k_step<true,  false><<<grid, block, 0, stream>>>(phi, inv, runoff, runoff, qA, nullptr, nullptr);
    k_step<false, false><<<grid, block, 0, stream>>>(phi, inv, runoff, qA, qB, nullptr, nullptr);
    k_step<false, false><<<grid, block, 0, stream>>>(phi, inv, runoff, qB, qA, nullptr, nullptr);
    k_step<false, true ><<<grid, block, 0, stream>>>(phi, inv, runoff, qA, out, cond, status);
}